// Round 3
// baseline (833.524 us; speedup 1.0000x reference)
//
#include <hip/hip_runtime.h>
#include <hip/hip_bf16.h>
#include <math.h>

// Problem constants (B=2, T=2048, D=1024, H=4096, E=8, TOP_K=2)
#define NTOK 4096
#define DDIM 1024
#define HDIM 4096
#define NEXP 8
#define CAP  4096          // per-expert token-list capacity (worst case)
#define ROWCAP 10240       // max padded rows: 40 tiles * 256 (sum ceil <= 40)
#define MAXTILES 40        // sum ceil(c_e/256) <= 8192/256 + 8 = 40

typedef __attribute__((ext_vector_type(8))) short short8;   // 8 bf16 (4 VGPRs)
typedef __attribute__((ext_vector_type(4))) float f32x4;

#define GLOAD_LDS16(g, l) __builtin_amdgcn_global_load_lds( \
    (const __attribute__((address_space(1))) void*)(g),     \
    (__attribute__((address_space(3))) void*)(l), 16, 0, 0)
// aux=2 -> nt (non-temporal / evict-first): stream-once A data must not
// evict the L2-resident B panel (cache-residency fix for round-2's 3x FETCH).
#define GLOAD_LDS16_NT(g, l) __builtin_amdgcn_global_load_lds( \
    (const __attribute__((address_space(1))) void*)(g),        \
    (__attribute__((address_space(3))) void*)(l), 16, 0, 2)

// ---------------------------------------------------------------- gating
__global__ __launch_bounds__(256) void gating_kernel(
    const float* __restrict__ x, const float* __restrict__ gw,
    const float* __restrict__ gb, float* __restrict__ logits_out,
    int* __restrict__ counts, int* __restrict__ tok, float* __restrict__ gate,
    int* __restrict__ eA, int* __restrict__ sA, float* __restrict__ gA) {
  int t = blockIdx.x;
  int tid = threadIdx.x;
  float p[NEXP];
#pragma unroll
  for (int e = 0; e < NEXP; ++e) p[e] = 0.f;
  const float* xr = x + (size_t)t * DDIM;
  for (int d = tid; d < DDIM; d += 256) {
    float xv = xr[d];
    const float* wr = gw + (size_t)d * NEXP;
#pragma unroll
    for (int e = 0; e < NEXP; ++e) p[e] += xv * wr[e];
  }
#pragma unroll
  for (int off = 32; off > 0; off >>= 1)
#pragma unroll
    for (int e = 0; e < NEXP; ++e) p[e] += __shfl_xor(p[e], off, 64);
  __shared__ float red[4][NEXP];
  int wave = tid >> 6, lane = tid & 63;
  if (lane == 0)
#pragma unroll
    for (int e = 0; e < NEXP; ++e) red[wave][e] = p[e];
  __syncthreads();
  if (tid < NEXP) {
    float v = red[0][tid] + red[1][tid] + red[2][tid] + red[3][tid] + gb[tid];
    logits_out[(size_t)t * NEXP + tid] = v;
    red[0][tid] = v;
  }
  __syncthreads();
  if (tid == 0) {
    float v[NEXP];
#pragma unroll
    for (int e = 0; e < NEXP; ++e) v[e] = red[0][e];
    int i0 = 0;
#pragma unroll
    for (int e = 1; e < NEXP; ++e) if (v[e] > v[i0]) i0 = e;
    int i1 = (i0 == 0) ? 1 : 0;
#pragma unroll
    for (int e = 0; e < NEXP; ++e) if (e != i0 && v[e] > v[i1]) i1 = e;
    float e1 = expf(v[i1] - v[i0]);          // v[i0] is the max
    float s = 1.f + e1;
    float g0 = 1.f / s, g1 = e1 / s;
    int s0 = atomicAdd(&counts[i0], 1);
    tok[i0 * CAP + s0] = t; gate[i0 * CAP + s0] = g0;
    int s1 = atomicAdd(&counts[i1], 1);
    tok[i1 * CAP + s1] = t; gate[i1 * CAP + s1] = g1;
    eA[2 * t] = i0; sA[2 * t] = s0; gA[2 * t] = g0;
    eA[2 * t + 1] = i1; sA[2 * t + 1] = s1; gA[2 * t + 1] = g1;
  }
}

// ---------------------------------------------------------------- schedule
// 256-row tiles (BM=256 for the 8-wave pipelined GEMM)
__global__ void sched_kernel(const int* __restrict__ counts, int* __restrict__ poff,
                             int* __restrict__ tileE, int* __restrict__ tileR,
                             int* __restrict__ nTiles) {
  if (threadIdx.x == 0) {
    int acc = 0, nt = 0;
    for (int e = 0; e < NEXP; ++e) {
      poff[e] = acc;
      int tl = (counts[e] + 255) >> 8;
      for (int t = 0; t < tl; ++t) { tileE[nt] = e; tileR[nt] = acc + t * 256; ++nt; }
      acc += tl << 8;
    }
    poff[NEXP] = acc;
    nTiles[0] = nt;
  }
}

// ------------------------------------------- fp32 [E][R][C] -> bf16 [E][C][R]
__global__ __launch_bounds__(256) void transpose_all(
    const float* __restrict__ w1, const float* __restrict__ w2,
    __hip_bfloat16* __restrict__ wT1, __hip_bfloat16* __restrict__ wT2) {
  __shared__ float tile[64 * 65];   // stride 65: 2-way max on both phases
  int id = blockIdx.x;
  const float* inp; __hip_bfloat16* outp; int R, C, bx, by;
  if (id < 8192) {                  // w1: [e][1024][4096] -> wT1 [e][4096][1024]
    int e = id >> 10, rem = id & 1023;
    bx = rem & 63; by = rem >> 6;   // 64 c-tiles, 16 r-tiles
    R = 1024; C = 4096;
    inp = w1 + (size_t)e * R * C; outp = wT1 + (size_t)e * R * C;
  } else {                          // w2: [e][4096][1024] -> wT2 [e][1024][4096]
    id -= 8192;
    int e = id >> 10, rem = id & 1023;
    bx = rem & 15; by = rem >> 4;   // 16 c-tiles, 64 r-tiles
    R = 4096; C = 1024;
    inp = w2 + (size_t)e * R * C; outp = wT2 + (size_t)e * R * C;
  }
  int c0 = bx * 64, r0 = by * 64;
  int tx = threadIdx.x & 15, ty = threadIdx.x >> 4;   // tx: 16 x float4 per row
#pragma unroll
  for (int i = 0; i < 64; i += 16) {
    float4 v = *(const float4*)(inp + (size_t)(r0 + ty + i) * C + c0 + tx * 4);
    float* dst = tile + (ty + i) * 65 + tx * 4;       // scalar: 65 breaks 16B align
    dst[0] = v.x; dst[1] = v.y; dst[2] = v.z; dst[3] = v.w;
  }
  __syncthreads();
  int c = threadIdx.x >> 3;          // 32 output rows (cols of input) per pass
  int rb = (threadIdx.x & 7) * 8;    // 8 bf16 along R per lane
#pragma unroll
  for (int p = 0; p < 2; ++p) {
    int cc = c + p * 32;
    union { unsigned short u[8]; short8 v8; } pk;
#pragma unroll
    for (int j = 0; j < 8; ++j) {
      __hip_bfloat16 h = __float2bfloat16(tile[(rb + j) * 65 + cc]);
      pk.u[j] = *(unsigned short*)&h;
    }
    *(short8*)(outp + (size_t)(c0 + cc) * R + r0 + rb) = pk.v8;
  }
}

// ---------------------------------- gather tokens, scale by gate, cast bf16
__global__ __launch_bounds__(256) void gather_kernel(
    const float* __restrict__ x, const int* __restrict__ counts,
    const int* __restrict__ poff, const int* __restrict__ tok,
    const float* __restrict__ gate, __hip_bfloat16* __restrict__ Xg) {
  int e = blockIdx.y, r = blockIdx.x;
  int pc = poff[e + 1] - poff[e];
  if (r >= pc) return;
  int row = poff[e] + r;
  int tid = threadIdx.x;
  __hip_bfloat16* orow = Xg + (size_t)row * DDIM;
  if (r < counts[e]) {
    int t = tok[e * CAP + r];
    float g = gate[e * CAP + r];
    float4 v = ((const float4*)(x + (size_t)t * DDIM))[tid];
    union { unsigned short u[4]; uint2 q; } pk;
    __hip_bfloat16 h0 = __float2bfloat16(v.x * g);
    __hip_bfloat16 h1 = __float2bfloat16(v.y * g);
    __hip_bfloat16 h2 = __float2bfloat16(v.z * g);
    __hip_bfloat16 h3 = __float2bfloat16(v.w * g);
    pk.u[0] = *(unsigned short*)&h0; pk.u[1] = *(unsigned short*)&h1;
    pk.u[2] = *(unsigned short*)&h2; pk.u[3] = *(unsigned short*)&h3;
    ((uint2*)orow)[tid] = pk.q;
  } else {
    uint2 z; z.x = 0; z.y = 0;
    ((uint2*)orow)[tid] = z;    // zero pad rows so GEMM1 reads zeros
  }
}

// ---------------------------------------------------------------- grouped GEMM
// 8-wave (512-thr) 256x128xBK64, triple-buffered, depth-2 prefetch,
// counted vmcnt (T4), two-phase MFMA split (T3-lite), setprio (T5),
// XOR LDS swizzle (T2), NT cache policy on A-staging (residency fix).
// A: [rows][K] bf16 (k-contig), B: [E][Nn][K] bf16 (k-contig, pre-transposed)
// EPI=0: Hout = bf16(gelu(acc + b1));  EPI=1: split-K fp32 partials.
//
// Per K-tile t: issue tile t+2's 6 global_load_lds (A nt, B cached) into
// buf[(t+2)%3]; phase A: ds_read B frags + half A frags, lgkmcnt(0),
// 16 MFMA under setprio; mid-barrier; phase B: rest of A frags, 16 MFMA;
// s_waitcnt vmcnt(6) (t+1 landed, t+2 in flight - never drain to 0 in
// steady state); one closing s_barrier. Buffer reuse safe: lgkmcnt(0)
// precedes barrier arrival, so buf[b] fully read before t+3 restages it.
// NT on A: A panels are stream-once per XCD; without nt they LRU-evict the
// 1MB/expert B slice from the 4MB XCD L2 when blocks drift in K (round-2
// counter evidence: FETCH 115->328 MB when lockstep was removed).
template <int EPI>
__global__ __launch_bounds__(512) void moe_gemm(
    const __hip_bfloat16* __restrict__ A, const __hip_bfloat16* __restrict__ B,
    const float* __restrict__ bias, __hip_bfloat16* __restrict__ Hout,
    float* __restrict__ Pout, const int* __restrict__ tileE,
    const int* __restrict__ tileR, const int* __restrict__ nTiles,
    int K, int Nn) {
  int f = (blockIdx.z * gridDim.y + blockIdx.y) * gridDim.x + blockIdx.x;
  int xcd = f & 7, seq = f >> 3;
  int ct, ty, kz;
  if (EPI == 0) {            // grid 32x40: 4 col tiles per XCD
    ct = xcd * 4 + (seq & 3); ty = seq >> 2; kz = 0;
  } else {                   // grid 8x40x2: 1 col tile per XCD (B L2-pinned)
    ct = xcd; ty = seq % MAXTILES; kz = seq / MAXTILES;
  }
  if (ty >= nTiles[0]) return;
  int e = tileE[ty];
  int rowBase = tileR[ty];
  int colBase = ct * 128;

  __shared__ __align__(16) char LA[98304];   // A: 3 x 32 KB (256 rows x 128B)
  __shared__ __align__(16) char LB[49152];   // B: 3 x 16 KB (128 cols x 128B)

  const char* Ae = (const char*)A + (size_t)rowBase * K * 2;
  const char* Be = (const char*)B + ((size_t)e * Nn + colBase) * (size_t)K * 2;

  int tid = threadIdx.x;
  int lane = tid & 63, wave = tid >> 6;
  int wm = (wave >> 1) * 64, wn = (wave & 1) * 64;   // 4x2 waves of 64x64
  int frm = lane & 15, g = lane >> 4;

  // staging: thread covers row sr (+64 per issue), 16B slot (tid&7);
  // source chunk = slot ^ (row&7)  (row&7 invariant across the +64 steps)
  int sr = tid >> 3;
  int sch = (tid & 7) ^ (sr & 7);
  const char* aS = Ae + (size_t)sr * K * 2 + sch * 16;
  const char* bS = Be + (size_t)sr * K * 2 + sch * 16;
  char* dA = LA + tid * 16;
  char* dB = LB + tid * 16;
  size_t rstep = (size_t)64 * K * 2;

  // frag reads: row = wm|wn + i*16 + frm; chunk(ks) = ks*4+g; slot = chunk^(frm&7)
  int f7 = frm & 7;
  int sl0 = (g ^ f7) << 4;
  int sl1 = ((4 + g) ^ f7) << 4;
  const char* rA = LA + (wm + frm) * 128;
  const char* rB = LB + (wn + frm) * 128;

  f32x4 acc[4][4] = {};
  int kPer = (EPI == 1) ? (K >> 1) : K;
  int kLo = kz * kPer;
  int NT = kPer >> 6;                         // >= 16 always
  const char* aP = aS + (size_t)kLo * 2;
  const char* bP = bS + (size_t)kLo * 2;

  // ---- prologue: stage K-tiles 0 and 1 into buffers 0 and 1
#pragma unroll
  for (int tt = 0; tt < 2; ++tt) {
    const char* a = aP + tt * 128;
    const char* b = bP + tt * 128;
    char* da = dA + tt * 32768;
    char* db = dB + tt * 16384;
#pragma unroll
    for (int j = 0; j < 4; ++j) GLOAD_LDS16_NT(a + j * rstep, da + j * 8192);
#pragma unroll
    for (int j = 0; j < 2; ++j) GLOAD_LDS16(b + j * rstep, db + j * 8192);
  }
  asm volatile("s_waitcnt vmcnt(6)" ::: "memory");   // tile 0 landed
  __builtin_amdgcn_sched_barrier(0);
  __builtin_amdgcn_s_barrier();

  int rbuf = 0, nbuf = 2;
  for (int t = 0; t < NT; ++t) {
    // ---- issue tile t+2 staging into buf[(t+2)%3] (in flight past barrier)
    if (t + 2 < NT) {
      const char* a = aP + (size_t)(t + 2) * 128;
      const char* b = bP + (size_t)(t + 2) * 128;
      char* da = dA + nbuf * 32768;
      char* db = dB + nbuf * 16384;
#pragma unroll
      for (int j = 0; j < 4; ++j) GLOAD_LDS16_NT(a + j * rstep, da + j * 8192);
#pragma unroll
      for (int j = 0; j < 2; ++j) GLOAD_LDS16(b + j * rstep, db + j * 8192);
    }
    const char* Ab = rA + rbuf * 32768;
    const char* Bb = rB + rbuf * 16384;
    short8 af[2][2], bfr[4][2], ag[2][2];
    // ---- phase A: B frags + first half of A frags -> 16 MFMA
#pragma unroll
    for (int j = 0; j < 4; ++j) {
      bfr[j][0] = *(const short8*)(Bb + j * 2048 + sl0);
      bfr[j][1] = *(const short8*)(Bb + j * 2048 + sl1);
    }
#pragma unroll
    for (int i = 0; i < 2; ++i) {
      af[i][0] = *(const short8*)(Ab + i * 2048 + sl0);
      af[i][1] = *(const short8*)(Ab + i * 2048 + sl1);
    }
    asm volatile("s_waitcnt lgkmcnt(0)" ::: "memory");
    __builtin_amdgcn_sched_barrier(0);
    __builtin_amdgcn_s_setprio(1);
#pragma unroll
    for (int ks = 0; ks < 2; ++ks)
#pragma unroll
      for (int i = 0; i < 2; ++i)
#pragma unroll
        for (int j = 0; j < 4; ++j)
          acc[i][j] = __builtin_amdgcn_mfma_f32_16x16x32_bf16(
              af[i][ks], bfr[j][ks], acc[i][j], 0, 0, 0);
    __builtin_amdgcn_s_setprio(0);
    __builtin_amdgcn_s_barrier();   // mid barrier: wave role diversity
    // ---- phase B: remaining A frags -> 16 MFMA
#pragma unroll
    for (int i = 0; i < 2; ++i) {
      ag[i][0] = *(const short8*)(Ab + (i + 2) * 2048 + sl0);
      ag[i][1] = *(const short8*)(Ab + (i + 2) * 2048 + sl1);
    }
    asm volatile("s_waitcnt lgkmcnt(0)" ::: "memory");
    __builtin_amdgcn_sched_barrier(0);
    __builtin_amdgcn_s_setprio(1);
#pragma unroll
    for (int ks = 0; ks < 2; ++ks)
#pragma unroll
      for (int i = 0; i < 2; ++i)
#pragma unroll
        for (int j = 0; j < 4; ++j)
          acc[i + 2][j] = __builtin_amdgcn_mfma_f32_16x16x32_bf16(
              ag[i][ks], bfr[j][ks], acc[i + 2][j], 0, 0, 0);
    __builtin_amdgcn_s_setprio(0);
    // ---- boundary: tile t+1 must be in LDS; t+2's 6 loads stay in flight
    if (t + 2 < NT) {
      asm volatile("s_waitcnt vmcnt(6)" ::: "memory");
    } else {
      asm volatile("s_waitcnt vmcnt(0)" ::: "memory");
    }
    __builtin_amdgcn_sched_barrier(0);
    __builtin_amdgcn_s_barrier();
    rbuf = (rbuf + 1 == 3) ? 0 : rbuf + 1;
    nbuf = (nbuf + 1 == 3) ? 0 : nbuf + 1;
  }

  // C/D layout: col = lane&15, row = (lane>>4)*4 + reg   [m89/m91 verified]
  int cq = lane >> 4, cn = lane & 15;
  if (EPI == 0) {
#pragma unroll
    for (int i = 0; i < 4; ++i) {
#pragma unroll
      for (int j = 0; j < 4; ++j) {
        int col = colBase + wn + j * 16 + cn;
        float bv = bias[e * Nn + col];
#pragma unroll
        for (int r = 0; r < 4; ++r) {
          int row = rowBase + wm + i * 16 + cq * 4 + r;
          float v = acc[i][j][r] + bv;
          // tanh-approx GELU in sigmoid form: v*sigma(1.59577*(v+0.044715 v^3))
          float z = 1.5957691f * v * (1.0f + 0.044715f * v * v);
          v = v / (1.0f + __expf(-z));
          Hout[(size_t)row * Nn + col] = __float2bfloat16(v);
        }
      }
    }
  } else {
    float* Pp = Pout + ((size_t)kz * ROWCAP + rowBase) * DDIM;
#pragma unroll
    for (int i = 0; i < 4; ++i) {
#pragma unroll
      for (int j = 0; j < 4; ++j) {
        int col = colBase + wn + j * 16 + cn;
#pragma unroll
        for (int r = 0; r < 4; ++r) {
          int row = wm + i * 16 + cq * 4 + r;
          Pp[(size_t)row * DDIM + col] = acc[i][j][r];
        }
      }
    }
  }
}

// ---------------------------------------------------------------- combine
// out[t][d] = sum_a g_a * (P0[row_a][d] + P1[row_a][d] + b2[e_a][d])
__global__ __launch_bounds__(256) void combine_kernel(
    const float* __restrict__ P, const float* __restrict__ b2,
    const int* __restrict__ poff, const int* __restrict__ eA,
    const int* __restrict__ sA, const float* __restrict__ gA,
    float* __restrict__ outF) {
  int t = blockIdx.x, c = threadIdx.x;   // c indexes float4 (256*4 = 1024 = D)
  int e0 = eA[2 * t], e1 = eA[2 * t + 1];
  int r0 = poff[e0] + sA[2 * t], r1 = poff[e1] + sA[2 * t + 1];
  float g0 = gA[2 * t], g1 = gA[2 * t + 1];
  float4 a0 = ((const float4*)(P + (size_t)r0 * DDIM))[c];
  float4 a1 = ((const float4*)(P + ((size_t)ROWCAP + r0) * DDIM))[c];
  float4 b0 = ((const float4*)(P + (size_t)r1 * DDIM))[c];
  float4 b1 = ((const float4*)(P + ((size_t)ROWCAP + r1) * DDIM))[c];
  float4 bb0 = ((const float4*)(b2 + (size_t)e0 * DDIM))[c];
  float4 bb1 = ((const float4*)(b2 + (size_t)e1 * DDIM))[c];
  float4 o;
  o.x = g0 * (a0.x + a1.x + bb0.x) + g1 * (b0.x + b1.x + bb1.x);
  o.y = g0 * (a0.y + a1.y + bb0.y) + g1 * (b0.y + b1.y + bb1.y);
  o.z = g0 * (a0.z + a1.z + bb0.z) + g1 * (b0.z + b1.z + bb1.z);
  o.w = g0 * (a0.w + a1.w + bb0.w) + g1 * (b0.w + b1.w + bb1.w);
  ((float4*)(outF + (size_t)t * DDIM))[c] = o;
}

// ---------------------------------------------------------------- launch
extern "C" void kernel_launch(void* const* d_in, const int* in_sizes, int n_in,
                              void* d_out, int out_size, void* d_ws, size_t ws_size,
                              hipStream_t stream) {
  const float* x  = (const float*)d_in[0];   // [4096][1024]
  const float* gw = (const float*)d_in[1];   // [1024][8]
  const float* gb = (const float*)d_in[2];   // [8]
  const float* w1 = (const float*)d_in[3];   // [8][1024][4096]
  const float* b1 = (const float*)d_in[4];   // [8][4096]
  const float* w2 = (const float*)d_in[5];   // [8][4096][1024]
  const float* b2 = (const float*)d_in[6];   // [8][1024]

  float* outF = (float*)d_out;                       // [4096][1024]
  float* outL = outF + (size_t)NTOK * DDIM;          // [4096][8]

  // workspace carve (~239 MB). P (split-K partials, fp32, 84 MB) aliases
  // wT1+Xg (88 MB), which are dead after GEMM1.
  size_t off = 0;
  char* base = (char*)d_ws;
  auto alloc = [&](size_t bytes) {
    void* r = base + off;
    off += (bytes + 255) & ~(size_t)255;
    return r;
  };
  __hip_bfloat16* wT1 = (__hip_bfloat16*)alloc((size_t)NEXP * HDIM * DDIM * 2);
  __hip_bfloat16* Xg  = (__hip_bfloat16*)alloc((size_t)ROWCAP * DDIM * 2);
  __hip_bfloat16* wT2 = (__hip_bfloat16*)alloc((size_t)NEXP * DDIM * HDIM * 2);
  __hip_bfloat16* Hact= (__hip_bfloat16*)alloc((size_t)ROWCAP * HDIM * 2);
  int*   tok    = (int*)alloc((size_t)NEXP * CAP * 4);
  float* gate   = (float*)alloc((size_t)NEXP * CAP * 4);
  int*   eA     = (int*)alloc((size_t)NTOK * 2 * 4);
  int*   sA     = (int*)alloc((size_t)NTOK * 2 * 4);
  float* gA     = (float*)alloc((size_t)NTOK * 2 * 4);
  int*   counts = (int*)alloc(64);
  int*   poff   = (int*)alloc(64);
  int*   tileE  = (int*)alloc(MAXTILES * 4);
  int*   tileR  = (int*)alloc(MAXTILES * 4);
  int*   nTiles = (int*)alloc(64);
  float* P      = (float*)wT1;   // [2][ROWCAP][DDIM] fp32, aliases wT1+Xg

  hipMemsetAsync(counts, 0, 64, stream);
  gating_kernel<<<NTOK, 256, 0, stream>>>(x, gw, gb, outL, counts, tok, gate, eA, sA, gA);
  sched_kernel<<<1, 64, 0, stream>>>(counts, poff, tileE, tileR, nTiles);
  transpose_all<<<16384, 256, 0, stream>>>(w1, w2, wT1, wT2);
  gather_kernel<<<dim3(CAP, NEXP), 256, 0, stream>>>(x, counts, poff, tok, gate, Xg);
  moe_gemm<0><<<dim3(HDIM / 128, MAXTILES, 1), 512, 0, stream>>>(
      Xg, wT1, b1, Hact, nullptr, tileE, tileR, nTiles, DDIM, HDIM);
  moe_gemm<1><<<dim3(DDIM / 128, MAXTILES, 2), 512, 0, stream>>>(
      Hact, wT2, b2, nullptr, P, tileE, tileR, nTiles, HDIM, DDIM);
  combine_kernel<<<NTOK, 256, 0, stream>>>(P, b2, poff, eA, sA, gA, outF);
}

// Round 4
// 696.730 us; speedup vs baseline: 1.1963x; 1.1963x over previous
//
#include <hip/hip_runtime.h>
#include <hip/hip_bf16.h>
#include <math.h>

// Problem constants (B=2, T=2048, D=1024, H=4096, E=8, TOP_K=2)
#define NTOK 4096
#define DDIM 1024
#define HDIM 4096
#define NEXP 8
#define CAP  4096          // per-expert token-list capacity (worst case)
#define ROWCAP 10240       // max padded rows: 40 tiles * 256
#define MAXTILES 40        // sum ceil(c_e/256) <= 8192/256 + 8 = 40

typedef __attribute__((ext_vector_type(8))) short short8;   // 8 bf16 (4 VGPRs)
typedef __attribute__((ext_vector_type(4))) float f32x4;

#define GLOAD_LDS16(g, l) __builtin_amdgcn_global_load_lds( \
    (const __attribute__((address_space(1))) void*)(g),     \
    (__attribute__((address_space(3))) void*)(l), 16, 0, 0)

// ---------------------------------------------------------------- gating
__global__ __launch_bounds__(256) void gating_kernel(
    const float* __restrict__ x, const float* __restrict__ gw,
    const float* __restrict__ gb, float* __restrict__ logits_out,
    int* __restrict__ counts, int* __restrict__ tok, float* __restrict__ gate,
    int* __restrict__ eA, int* __restrict__ sA, float* __restrict__ gA) {
  int t = blockIdx.x;
  int tid = threadIdx.x;
  float p[NEXP];
#pragma unroll
  for (int e = 0; e < NEXP; ++e) p[e] = 0.f;
  const float* xr = x + (size_t)t * DDIM;
  for (int d = tid; d < DDIM; d += 256) {
    float xv = xr[d];
    const float* wr = gw + (size_t)d * NEXP;
#pragma unroll
    for (int e = 0; e < NEXP; ++e) p[e] += xv * wr[e];
  }
#pragma unroll
  for (int off = 32; off > 0; off >>= 1)
#pragma unroll
    for (int e = 0; e < NEXP; ++e) p[e] += __shfl_xor(p[e], off, 64);
  __shared__ float red[4][NEXP];
  int wave = tid >> 6, lane = tid & 63;
  if (lane == 0)
#pragma unroll
    for (int e = 0; e < NEXP; ++e) red[wave][e] = p[e];
  __syncthreads();
  if (tid < NEXP) {
    float v = red[0][tid] + red[1][tid] + red[2][tid] + red[3][tid] + gb[tid];
    logits_out[(size_t)t * NEXP + tid] = v;
    red[0][tid] = v;
  }
  __syncthreads();
  if (tid == 0) {
    float v[NEXP];
#pragma unroll
    for (int e = 0; e < NEXP; ++e) v[e] = red[0][e];
    int i0 = 0;
#pragma unroll
    for (int e = 1; e < NEXP; ++e) if (v[e] > v[i0]) i0 = e;
    int i1 = (i0 == 0) ? 1 : 0;
#pragma unroll
    for (int e = 0; e < NEXP; ++e) if (e != i0 && v[e] > v[i1]) i1 = e;
    float e1 = expf(v[i1] - v[i0]);          // v[i0] is the max
    float s = 1.f + e1;
    float g0 = 1.f / s, g1 = e1 / s;
    int s0 = atomicAdd(&counts[i0], 1);
    tok[i0 * CAP + s0] = t; gate[i0 * CAP + s0] = g0;
    int s1 = atomicAdd(&counts[i1], 1);
    tok[i1 * CAP + s1] = t; gate[i1 * CAP + s1] = g1;
    eA[2 * t] = i0; sA[2 * t] = s0; gA[2 * t] = g0;
    eA[2 * t + 1] = i1; sA[2 * t + 1] = s1; gA[2 * t + 1] = g1;
  }
}

// ---------------------------------------------------------------- schedule
// 256-row tiles (BM=256 for the 8-wave pipelined GEMM)
__global__ void sched_kernel(const int* __restrict__ counts, int* __restrict__ poff,
                             int* __restrict__ tileE, int* __restrict__ tileR,
                             int* __restrict__ nTiles) {
  if (threadIdx.x == 0) {
    int acc = 0, nt = 0;
    for (int e = 0; e < NEXP; ++e) {
      poff[e] = acc;
      int tl = (counts[e] + 255) >> 8;
      for (int t = 0; t < tl; ++t) { tileE[nt] = e; tileR[nt] = acc + t * 256; ++nt; }
      acc += tl << 8;
    }
    poff[NEXP] = acc;
    nTiles[0] = nt;
  }
}

// ------------------------------------------- fp32 [E][R][C] -> bf16 [E][C][R]
__global__ __launch_bounds__(256) void transpose_all(
    const float* __restrict__ w1, const float* __restrict__ w2,
    __hip_bfloat16* __restrict__ wT1, __hip_bfloat16* __restrict__ wT2) {
  __shared__ float tile[64 * 65];   // stride 65: 2-way max on both phases
  int id = blockIdx.x;
  const float* inp; __hip_bfloat16* outp; int R, C, bx, by;
  if (id < 8192) {                  // w1: [e][1024][4096] -> wT1 [e][4096][1024]
    int e = id >> 10, rem = id & 1023;
    bx = rem & 63; by = rem >> 6;   // 64 c-tiles, 16 r-tiles
    R = 1024; C = 4096;
    inp = w1 + (size_t)e * R * C; outp = wT1 + (size_t)e * R * C;
  } else {                          // w2: [e][4096][1024] -> wT2 [e][1024][4096]
    id -= 8192;
    int e = id >> 10, rem = id & 1023;
    bx = rem & 15; by = rem >> 4;   // 16 c-tiles, 64 r-tiles
    R = 4096; C = 1024;
    inp = w2 + (size_t)e * R * C; outp = wT2 + (size_t)e * R * C;
  }
  int c0 = bx * 64, r0 = by * 64;
  int tx = threadIdx.x & 15, ty = threadIdx.x >> 4;   // tx: 16 x float4 per row
#pragma unroll
  for (int i = 0; i < 64; i += 16) {
    float4 v = *(const float4*)(inp + (size_t)(r0 + ty + i) * C + c0 + tx * 4);
    float* dst = tile + (ty + i) * 65 + tx * 4;       // scalar: 65 breaks 16B align
    dst[0] = v.x; dst[1] = v.y; dst[2] = v.z; dst[3] = v.w;
  }
  __syncthreads();
  int c = threadIdx.x >> 3;          // 32 output rows (cols of input) per pass
  int rb = (threadIdx.x & 7) * 8;    // 8 bf16 along R per lane
#pragma unroll
  for (int p = 0; p < 2; ++p) {
    int cc = c + p * 32;
    union { unsigned short u[8]; short8 v8; } pk;
#pragma unroll
    for (int j = 0; j < 8; ++j) {
      __hip_bfloat16 h = __float2bfloat16(tile[(rb + j) * 65 + cc]);
      pk.u[j] = *(unsigned short*)&h;
    }
    *(short8*)(outp + (size_t)(c0 + cc) * R + r0 + rb) = pk.v8;
  }
}

// ---------------------------------- gather tokens, scale by gate, cast bf16
__global__ __launch_bounds__(256) void gather_kernel(
    const float* __restrict__ x, const int* __restrict__ counts,
    const int* __restrict__ poff, const int* __restrict__ tok,
    const float* __restrict__ gate, __hip_bfloat16* __restrict__ Xg) {
  int e = blockIdx.y, r = blockIdx.x;
  int pc = poff[e + 1] - poff[e];
  if (r >= pc) return;
  int row = poff[e] + r;
  int tid = threadIdx.x;
  __hip_bfloat16* orow = Xg + (size_t)row * DDIM;
  if (r < counts[e]) {
    int t = tok[e * CAP + r];
    float g = gate[e * CAP + r];
    float4 v = ((const float4*)(x + (size_t)t * DDIM))[tid];
    union { unsigned short u[4]; uint2 q; } pk;
    __hip_bfloat16 h0 = __float2bfloat16(v.x * g);
    __hip_bfloat16 h1 = __float2bfloat16(v.y * g);
    __hip_bfloat16 h2 = __float2bfloat16(v.z * g);
    __hip_bfloat16 h3 = __float2bfloat16(v.w * g);
    pk.u[0] = *(unsigned short*)&h0; pk.u[1] = *(unsigned short*)&h1;
    pk.u[2] = *(unsigned short*)&h2; pk.u[3] = *(unsigned short*)&h3;
    ((uint2*)orow)[tid] = pk.q;
  } else {
    uint2 z; z.x = 0; z.y = 0;
    ((uint2*)orow)[tid] = z;    // zero pad rows so GEMM1 reads zeros
  }
}

// ---------------------------------------------------------------- grouped GEMM
// m201-style 8-phase 256x256xBK64 schedule (T2+T3+T4+T5), 8 waves (512 thr),
// per-wave output 128x64 (2M x 4N wave grid), double-buffered 128 KB LDS.
// A: [rows][K] bf16 (k-contig), B: [E][Nn][K] bf16 (k-contig, pre-transposed)
// EPI=0: Hout = bf16(gelu(acc + b1));  EPI=1: split-K fp32 partials.
//
// Per K-tile: 4 sub-phases, each = { ds_read frag subtile (4-12 b128) ||
// stage 2 x 8KB slabs of tile t+1 -> s_barrier -> lgkmcnt(0) -> setprio(1)
// 16 MFMA setprio(0) -> [counted vmcnt] -> s_barrier }.
// Slab stage order per tile: P0:{B0,B1} P1:{B2,B3} P2:{A0,A2} P3:{A1,A3}.
// Slab consumption (tile t+1): P0 needs B(all)+A0+A2 (6 oldest), P2 needs
// A1+A3. Hence: vmcnt(4) at end of P1 (waits A1,A3 of current tile),
// vmcnt(2) at end of P3 (waits 6 oldest of next tile) -- never drains to 0
// in steady state; last tile uses vmcnt(0) at P1.
// Swizzle (T2, verified 0 conflicts): 16B slot s of row r holds global
// k-chunk s^(r&7); inverse-swizzled global source, same XOR on ds_read.
template <int EPI>
__global__ __launch_bounds__(512, 2) void moe_gemm(
    const __hip_bfloat16* __restrict__ A, const __hip_bfloat16* __restrict__ B,
    const float* __restrict__ bias, __hip_bfloat16* __restrict__ Hout,
    float* __restrict__ Pout, const int* __restrict__ tileE,
    const int* __restrict__ tileR, const int* __restrict__ nTiles,
    int K, int Nn) {
  int f = blockIdx.y * gridDim.x + blockIdx.x;
  int xcd = f & 7, seq = f >> 3;
  int ct, ty, kz;
  if (EPI == 0) {            // 16 col tiles: 2 per XCD
    ct = xcd * 2 + (seq & 1); ty = seq >> 1; kz = 0;
  } else {                   // 4 col tiles x 2 kz = 8 combos: 1 per XCD
    ct = xcd & 3; kz = xcd >> 2; ty = seq;
  }
  if (ty >= nTiles[0]) return;
  int e = tileE[ty];
  int rowBase = tileR[ty];
  int colBase = ct * 256;

  __shared__ __align__(16) char LA[65536];   // 2 buf x 256 rows x 128 B
  __shared__ __align__(16) char LB[65536];   // 2 buf x 256 cols x 128 B

  const char* Ae = (const char*)A + (size_t)rowBase * K * 2;
  const char* Be = (const char*)B + ((size_t)e * Nn + colBase) * (size_t)K * 2;

  int tid = threadIdx.x;
  int lane = tid & 63, wave = tid >> 6;
  int wm = (wave >> 2) * 128, wn = (wave & 3) * 64;   // 2M x 4N waves, 128x64 each
  int frm = lane & 15, g = lane >> 4;

  // staging: thread covers row sr of each 64-row slab, 16B slot (tid&7);
  // source chunk = slot ^ (row&7)  (row&7 invariant across slabs)
  int sr = tid >> 3;
  int sch = (tid & 7) ^ (sr & 7);
  const char* aS = Ae + (size_t)sr * K * 2 + sch * 16;
  const char* bS = Be + (size_t)sr * K * 2 + sch * 16;
  size_t rstep = (size_t)64 * K * 2;   // 64-row slab stride in global

  // frag reads: row = wm|wn + fragidx*16 + frm; chunk(ks) = ks*4+g;
  // slot = chunk ^ (row&7) = chunk ^ (frm&7)
  int f7 = frm & 7;
  int sl0 = (g ^ f7) << 4;
  int sl1 = ((4 + g) ^ f7) << 4;
  const char* rA = LA + (wm + frm) * 128;
  const char* rB = LB + (wn + frm) * 128;

  f32x4 acc[8][4] = {};
  int kPer = (EPI == 1) ? (K >> 1) : K;
  int kLo = kz * kPer;
  int NT = kPer >> 6;                         // 16 (GEMM1) / 32 (GEMM2)
  const char* aP = aS + (size_t)kLo * 2;
  const char* bP = bS + (size_t)kLo * 2;

  auto stageA = [&](int t, int s, int b) {
    GLOAD_LDS16(aP + (size_t)t * 128 + (size_t)s * rstep,
                LA + b * 32768 + s * 8192 + tid * 16);
  };
  auto stageB = [&](int t, int s, int b) {
    GLOAD_LDS16(bP + (size_t)t * 128 + (size_t)s * rstep,
                LB + b * 32768 + s * 8192 + tid * 16);
  };

  // ---- prologue: tile 0 into buf 0, boundary-convention order
  stageB(0, 0, 0); stageB(0, 1, 0); stageB(0, 2, 0); stageB(0, 3, 0);
  stageA(0, 0, 0); stageA(0, 2, 0); stageA(0, 1, 0); stageA(0, 3, 0);
  asm volatile("s_waitcnt vmcnt(2)" ::: "memory");   // 6 oldest landed; A1,A3 in flight
  __builtin_amdgcn_sched_barrier(0);
  __builtin_amdgcn_s_barrier();

  for (int t = 0; t < NT; ++t) {
    int rb = t & 1, sb = rb ^ 1;
    const char* Ab = rA + rb * 32768;
    const char* Bb = rB + rb * 32768;
    bool pre = (t + 1 < NT);
    short8 bfr[4][2];
#pragma unroll 4
    for (int p = 0; p < 4; ++p) {
      short8 af[2][2];
      if (p == 0) {          // all B frags for this tile (own 64-col slab)
#pragma unroll
        for (int n = 0; n < 4; ++n) {
          bfr[n][0] = *(const short8*)(Bb + (n * 16) * 128 + sl0);
          bfr[n][1] = *(const short8*)(Bb + (n * 16) * 128 + sl1);
        }
      }
#pragma unroll
      for (int i = 0; i < 2; ++i) {   // A frags m = 2p, 2p+1
        af[i][0] = *(const short8*)(Ab + ((p * 2 + i) * 16) * 128 + sl0);
        af[i][1] = *(const short8*)(Ab + ((p * 2 + i) * 16) * 128 + sl1);
      }
      if (pre) {             // stage 2 slabs of tile t+1
        if (p == 0)      { stageB(t + 1, 0, sb); stageB(t + 1, 1, sb); }
        else if (p == 1) { stageB(t + 1, 2, sb); stageB(t + 1, 3, sb); }
        else if (p == 2) { stageA(t + 1, 0, sb); stageA(t + 1, 2, sb); }
        else             { stageA(t + 1, 1, sb); stageA(t + 1, 3, sb); }
      }
      __builtin_amdgcn_s_barrier();
      asm volatile("s_waitcnt lgkmcnt(0)" ::: "memory");
      __builtin_amdgcn_sched_barrier(0);
      __builtin_amdgcn_s_setprio(1);
#pragma unroll
      for (int ks = 0; ks < 2; ++ks)
#pragma unroll
        for (int i = 0; i < 2; ++i)
#pragma unroll
          for (int n = 0; n < 4; ++n)
            acc[p * 2 + i][n] = __builtin_amdgcn_mfma_f32_16x16x32_bf16(
                af[i][ks], bfr[n][ks], acc[p * 2 + i][n], 0, 0, 0);
      __builtin_amdgcn_s_setprio(0);
      if (p == 1) {          // A1,A3 of THIS tile must land before P2 reads
        if (pre) asm volatile("s_waitcnt vmcnt(4)" ::: "memory");
        else     asm volatile("s_waitcnt vmcnt(0)" ::: "memory");
        __builtin_amdgcn_sched_barrier(0);
      } else if (p == 3 && pre) {   // 6 oldest of tile t+1 before its P0
        asm volatile("s_waitcnt vmcnt(2)" ::: "memory");
        __builtin_amdgcn_sched_barrier(0);
      }
      __builtin_amdgcn_s_barrier();
    }
  }

  // C/D layout: col = lane&15, row = (lane>>4)*4 + reg   [m89/m91 verified]
  int cq = lane >> 4, cn = lane & 15;
  if (EPI == 0) {
#pragma unroll
    for (int n = 0; n < 4; ++n) {
      int col = colBase + wn + n * 16 + cn;
      float bv = bias[e * Nn + col];
#pragma unroll
      for (int m = 0; m < 8; ++m) {
#pragma unroll
        for (int r = 0; r < 4; ++r) {
          int row = rowBase + wm + m * 16 + cq * 4 + r;
          float v = acc[m][n][r] + bv;
          // tanh-approx GELU in sigmoid form: v*sigma(1.59577*(v+0.044715 v^3))
          float z = 1.5957691f * v * (1.0f + 0.044715f * v * v);
          v = v / (1.0f + __expf(-z));
          Hout[(size_t)row * Nn + col] = __float2bfloat16(v);
        }
      }
    }
  } else {
    float* Pp = Pout + ((size_t)kz * ROWCAP + rowBase) * DDIM;
#pragma unroll
    for (int n = 0; n < 4; ++n) {
      int col = colBase + wn + n * 16 + cn;
#pragma unroll
      for (int m = 0; m < 8; ++m) {
#pragma unroll
        for (int r = 0; r < 4; ++r) {
          int row = wm + m * 16 + cq * 4 + r;
          Pp[(size_t)row * DDIM + col] = acc[m][n][r];
        }
      }
    }
  }
}

// ---------------------------------------------------------------- combine
// out[t][d] = sum_a g_a * (P0[row_a][d] + P1[row_a][d] + b2[e_a][d])
__global__ __launch_bounds__(256) void combine_kernel(
    const float* __restrict__ P, const float* __restrict__ b2,
    const int* __restrict__ poff, const int* __restrict__ eA,
    const int* __restrict__ sA, const float* __restrict__ gA,
    float* __restrict__ outF) {
  int t = blockIdx.x, c = threadIdx.x;   // c indexes float4 (256*4 = 1024 = D)
  int e0 = eA[2 * t], e1 = eA[2 * t + 1];
  int r0 = poff[e0] + sA[2 * t], r1 = poff[e1] + sA[2 * t + 1];
  float g0 = gA[2 * t], g1 = gA[2 * t + 1];
  float4 a0 = ((const float4*)(P + (size_t)r0 * DDIM))[c];
  float4 a1 = ((const float4*)(P + ((size_t)ROWCAP + r0) * DDIM))[c];
  float4 b0 = ((const float4*)(P + (size_t)r1 * DDIM))[c];
  float4 b1 = ((const float4*)(P + ((size_t)ROWCAP + r1) * DDIM))[c];
  float4 bb0 = ((const float4*)(b2 + (size_t)e0 * DDIM))[c];
  float4 bb1 = ((const float4*)(b2 + (size_t)e1 * DDIM))[c];
  float4 o;
  o.x = g0 * (a0.x + a1.x + bb0.x) + g1 * (b0.x + b1.x + bb1.x);
  o.y = g0 * (a0.y + a1.y + bb0.y) + g1 * (b0.y + b1.y + bb1.y);
  o.z = g0 * (a0.z + a1.z + bb0.z) + g1 * (b0.z + b1.z + bb1.z);
  o.w = g0 * (a0.w + a1.w + bb0.w) + g1 * (b0.w + b1.w + bb1.w);
  ((float4*)(outF + (size_t)t * DDIM))[c] = o;
}

// ---------------------------------------------------------------- launch
extern "C" void kernel_launch(void* const* d_in, const int* in_sizes, int n_in,
                              void* d_out, int out_size, void* d_ws, size_t ws_size,
                              hipStream_t stream) {
  const float* x  = (const float*)d_in[0];   // [4096][1024]
  const float* gw = (const float*)d_in[1];   // [1024][8]
  const float* gb = (const float*)d_in[2];   // [8]
  const float* w1 = (const float*)d_in[3];   // [8][1024][4096]
  const float* b1 = (const float*)d_in[4];   // [8][4096]
  const float* w2 = (const float*)d_in[5];   // [8][4096][1024]
  const float* b2 = (const float*)d_in[6];   // [8][1024]

  float* outF = (float*)d_out;                       // [4096][1024]
  float* outL = outF + (size_t)NTOK * DDIM;          // [4096][8]

  // workspace carve (~239 MB). P (split-K partials, fp32, 84 MB) aliases
  // wT1+Xg (88 MB), which are dead after GEMM1.
  size_t off = 0;
  char* base = (char*)d_ws;
  auto alloc = [&](size_t bytes) {
    void* r = base + off;
    off += (bytes + 255) & ~(size_t)255;
    return r;
  };
  __hip_bfloat16* wT1 = (__hip_bfloat16*)alloc((size_t)NEXP * HDIM * DDIM * 2);
  __hip_bfloat16* Xg  = (__hip_bfloat16*)alloc((size_t)ROWCAP * DDIM * 2);
  __hip_bfloat16* wT2 = (__hip_bfloat16*)alloc((size_t)NEXP * DDIM * HDIM * 2);
  __hip_bfloat16* Hact= (__hip_bfloat16*)alloc((size_t)ROWCAP * HDIM * 2);
  int*   tok    = (int*)alloc((size_t)NEXP * CAP * 4);
  float* gate   = (float*)alloc((size_t)NEXP * CAP * 4);
  int*   eA     = (int*)alloc((size_t)NTOK * 2 * 4);
  int*   sA     = (int*)alloc((size_t)NTOK * 2 * 4);
  float* gA     = (float*)alloc((size_t)NTOK * 2 * 4);
  int*   counts = (int*)alloc(64);
  int*   poff   = (int*)alloc(64);
  int*   tileE  = (int*)alloc(MAXTILES * 4);
  int*   tileR  = (int*)alloc(MAXTILES * 4);
  int*   nTiles = (int*)alloc(64);
  float* P      = (float*)wT1;   // [2][ROWCAP][DDIM] fp32, aliases wT1+Xg

  hipMemsetAsync(counts, 0, 64, stream);
  gating_kernel<<<NTOK, 256, 0, stream>>>(x, gw, gb, outL, counts, tok, gate, eA, sA, gA);
  sched_kernel<<<1, 64, 0, stream>>>(counts, poff, tileE, tileR, nTiles);
  transpose_all<<<16384, 256, 0, stream>>>(w1, w2, wT1, wT2);
  gather_kernel<<<dim3(CAP, NEXP), 256, 0, stream>>>(x, counts, poff, tok, gate, Xg);
  // GEMM1: 16 col-tiles (HDIM/256) x row-tiles
  moe_gemm<0><<<dim3(16, MAXTILES * 2 / 2, 1), 512, 0, stream>>>(
      Xg, wT1, b1, Hact, nullptr, tileE, tileR, nTiles, DDIM, HDIM);
  // GEMM2: 4 col-tiles (DDIM/256) x 2 split-K, 1 combo per XCD
  moe_gemm<1><<<dim3(8, MAXTILES, 1), 512, 0, stream>>>(
      Hact, wT2, b2, nullptr, P, tileE, tileR, nTiles, HDIM, DDIM);
  combine_kernel<<<NTOK, 256, 0, stream>>>(P, b2, poff, eA, sA, gA, outF);
}

// Round 5
// 673.636 us; speedup vs baseline: 1.2374x; 1.0343x over previous
//
#include <hip/hip_runtime.h>
#include <hip/hip_bf16.h>
#include <math.h>

// Problem constants (B=2, T=2048, D=1024, H=4096, E=8, TOP_K=2)
#define NTOK 4096
#define DDIM 1024
#define HDIM 4096
#define NEXP 8
#define CAP  4096          // per-expert token-list capacity (worst case)
#define ROWCAP 10240       // max padded rows: 40 tiles * 256
#define MAXTILES 40        // sum ceil(c_e/256) <= 8192/256 + 8 = 40

typedef __attribute__((ext_vector_type(8))) short short8;   // 8 bf16 (4 VGPRs)
typedef __attribute__((ext_vector_type(4))) float f32x4;

#define GLOAD_LDS16(g, l) __builtin_amdgcn_global_load_lds( \
    (const __attribute__((address_space(1))) void*)(g),     \
    (__attribute__((address_space(3))) void*)(l), 16, 0, 0)

// schedule lookup from counts: ty -> (expert, rowBase). 256-row tiles.
__device__ __forceinline__ int tile_lookup(const int* __restrict__ counts,
                                           int ty, int& e, int& rowBase) {
  int acc = 0;
#pragma unroll
  for (int ee = 0; ee < NEXP; ++ee) {
    int tl = (counts[ee] + 255) >> 8;
    if (ty < tl) { e = ee; rowBase = acc + ty * 256; return 1; }
    ty -= tl; acc += tl << 8;
  }
  return 0;
}

// ---------------------------------------------------------------- gating
__global__ __launch_bounds__(256) void gating_kernel(
    const float* __restrict__ x, const float* __restrict__ gw,
    const float* __restrict__ gb, float* __restrict__ logits_out,
    int* __restrict__ counts, int* __restrict__ tok, float* __restrict__ gate,
    int* __restrict__ eA, int* __restrict__ sA, float* __restrict__ gA) {
  int t = blockIdx.x;
  int tid = threadIdx.x;
  float p[NEXP];
#pragma unroll
  for (int e = 0; e < NEXP; ++e) p[e] = 0.f;
  const float* xr = x + (size_t)t * DDIM;
  for (int d = tid; d < DDIM; d += 256) {
    float xv = xr[d];
    const float* wr = gw + (size_t)d * NEXP;
#pragma unroll
    for (int e = 0; e < NEXP; ++e) p[e] += xv * wr[e];
  }
#pragma unroll
  for (int off = 32; off > 0; off >>= 1)
#pragma unroll
    for (int e = 0; e < NEXP; ++e) p[e] += __shfl_xor(p[e], off, 64);
  __shared__ float red[4][NEXP];
  int wave = tid >> 6, lane = tid & 63;
  if (lane == 0)
#pragma unroll
    for (int e = 0; e < NEXP; ++e) red[wave][e] = p[e];
  __syncthreads();
  if (tid < NEXP) {
    float v = red[0][tid] + red[1][tid] + red[2][tid] + red[3][tid] + gb[tid];
    logits_out[(size_t)t * NEXP + tid] = v;
    red[0][tid] = v;
  }
  __syncthreads();
  if (tid == 0) {
    float v[NEXP];
#pragma unroll
    for (int e = 0; e < NEXP; ++e) v[e] = red[0][e];
    int i0 = 0;
#pragma unroll
    for (int e = 1; e < NEXP; ++e) if (v[e] > v[i0]) i0 = e;
    int i1 = (i0 == 0) ? 1 : 0;
#pragma unroll
    for (int e = 0; e < NEXP; ++e) if (e != i0 && v[e] > v[i1]) i1 = e;
    float e1 = expf(v[i1] - v[i0]);          // v[i0] is the max
    float s = 1.f + e1;
    float g0 = 1.f / s, g1 = e1 / s;
    int s0 = atomicAdd(&counts[i0], 1);
    tok[i0 * CAP + s0] = t; gate[i0 * CAP + s0] = g0;
    int s1 = atomicAdd(&counts[i1], 1);
    tok[i1 * CAP + s1] = t; gate[i1 * CAP + s1] = g1;
    eA[2 * t] = i0; sA[2 * t] = s0; gA[2 * t] = g0;
    eA[2 * t + 1] = i1; sA[2 * t + 1] = s1; gA[2 * t + 1] = g1;
  }
}

// ------------------------------------------- fp32 [E][R][C] -> bf16 [E][C][R]
// Stores TRANSPOSED into LDS during load phase (scalar writes, 2-way banks);
// read phase is ds_read_b128 + coalesced 8B stores (was 64 scalar ds_read_b32).
__global__ __launch_bounds__(256) void transpose_all(
    const float* __restrict__ w1, const float* __restrict__ w2,
    __hip_bfloat16* __restrict__ wT1, __hip_bfloat16* __restrict__ wT2) {
  __shared__ float tileT[64 * 68];   // col-major [c][r], stride 68 (16B-aligned)
  int id = blockIdx.x;
  const float* inp; __hip_bfloat16* outp; int R, C, bx, by;
  if (id < 8192) {                  // w1: [e][1024][4096] -> wT1 [e][4096][1024]
    int e = id >> 10, rem = id & 1023;
    bx = rem & 63; by = rem >> 6;   // 64 c-tiles, 16 r-tiles
    R = 1024; C = 4096;
    inp = w1 + (size_t)e * R * C; outp = wT1 + (size_t)e * R * C;
  } else {                          // w2: [e][4096][1024] -> wT2 [e][1024][4096]
    id -= 8192;
    int e = id >> 10, rem = id & 1023;
    bx = rem & 15; by = rem >> 4;   // 16 c-tiles, 64 r-tiles
    R = 4096; C = 1024;
    inp = w2 + (size_t)e * R * C; outp = wT2 + (size_t)e * R * C;
  }
  int c0 = bx * 64, r0 = by * 64;
  int tx = threadIdx.x & 15, ty = threadIdx.x >> 4;   // tx: 16 x float4 per row
#pragma unroll
  for (int i = 0; i < 64; i += 16) {
    int rr = ty + i;
    float4 v = *(const float4*)(inp + (size_t)(r0 + rr) * C + c0 + tx * 4);
    tileT[(tx * 4 + 0) * 68 + rr] = v.x;
    tileT[(tx * 4 + 1) * 68 + rr] = v.y;
    tileT[(tx * 4 + 2) * 68 + rr] = v.z;
    tileT[(tx * 4 + 3) * 68 + rr] = v.w;
  }
  __syncthreads();
  int rb = (threadIdx.x & 15) * 4;   // 4 fp32 along R per lane (16B aligned)
#pragma unroll
  for (int p = 0; p < 4; ++p) {
    int cc = (threadIdx.x >> 4) + p * 16;
    float4 w = *(const float4*)(&tileT[cc * 68 + rb]);
    union { unsigned short u[4]; uint2 q; } pk;
    __hip_bfloat16 h0 = __float2bfloat16(w.x);
    __hip_bfloat16 h1 = __float2bfloat16(w.y);
    __hip_bfloat16 h2 = __float2bfloat16(w.z);
    __hip_bfloat16 h3 = __float2bfloat16(w.w);
    pk.u[0] = *(unsigned short*)&h0; pk.u[1] = *(unsigned short*)&h1;
    pk.u[2] = *(unsigned short*)&h2; pk.u[3] = *(unsigned short*)&h3;
    *(uint2*)(outp + (size_t)(c0 + cc) * R + r0 + rb) = pk.q;
  }
}

// ---------------------------------- gather tokens, scale by gate, cast bf16
// 1-D grid over padded rows; schedule derived inline from counts.
__global__ __launch_bounds__(256) void gather_kernel(
    const float* __restrict__ x, const int* __restrict__ counts,
    const int* __restrict__ tok, const float* __restrict__ gate,
    __hip_bfloat16* __restrict__ Xg) {
  int r = blockIdx.x;
  int acc = 0, e = -1, idx = 0;
#pragma unroll
  for (int ee = 0; ee < NEXP; ++ee) {
    int sz = (((counts[ee] + 255) >> 8) << 8);
    if (e < 0 && r < acc + sz) { e = ee; idx = r - acc; }
    acc += sz;
  }
  if (e < 0) return;
  int tid = threadIdx.x;
  __hip_bfloat16* orow = Xg + (size_t)r * DDIM;
  if (idx < counts[e]) {
    int t = tok[e * CAP + idx];
    float g = gate[e * CAP + idx];
    float4 v = ((const float4*)(x + (size_t)t * DDIM))[tid];
    union { unsigned short u[4]; uint2 q; } pk;
    __hip_bfloat16 h0 = __float2bfloat16(v.x * g);
    __hip_bfloat16 h1 = __float2bfloat16(v.y * g);
    __hip_bfloat16 h2 = __float2bfloat16(v.z * g);
    __hip_bfloat16 h3 = __float2bfloat16(v.w * g);
    pk.u[0] = *(unsigned short*)&h0; pk.u[1] = *(unsigned short*)&h1;
    pk.u[2] = *(unsigned short*)&h2; pk.u[3] = *(unsigned short*)&h3;
    ((uint2*)orow)[tid] = pk.q;
  } else {
    uint2 z; z.x = 0; z.y = 0;
    ((uint2*)orow)[tid] = z;    // zero pad rows so GEMM1 reads zeros
  }
}

// ---------------------------------------------------------------- grouped GEMM
// m201-style 8-phase 256x256xBK64 schedule (T2+T3+T4+T5), 8 waves (512 thr),
// per-wave output 128x64 (2M x 4N wave grid), double-buffered 128 KB LDS.
// K-loop IDENTICAL to round-4 (verified). New: LDS-staged coalesced epilogue
// (full-line global writes; fixes 2.4x write amplification seen in PMC).
template <int EPI>
__global__ __launch_bounds__(512, 2) void moe_gemm(
    const __hip_bfloat16* __restrict__ A, const __hip_bfloat16* __restrict__ B,
    const float* __restrict__ bias, __hip_bfloat16* __restrict__ Hout,
    float* __restrict__ Pout, const int* __restrict__ counts,
    int K, int Nn) {
  int f = blockIdx.y * gridDim.x + blockIdx.x;
  int xcd = f & 7, seq = f >> 3;
  int ct, ty, kz;
  if (EPI == 0) {            // 16 col tiles: 2 per XCD
    ct = xcd * 2 + (seq & 1); ty = seq >> 1; kz = 0;
  } else {                   // 4 col tiles x 2 kz = 8 combos: 1 per XCD
    ct = xcd & 3; kz = xcd >> 2; ty = seq;
  }
  int e, rowBase;
  if (!tile_lookup(counts, ty, e, rowBase)) return;
  int colBase = ct * 256;

  // union region: staging (2x32KB A + 2x32KB B) / epilogue stage (<=133120 B)
  __shared__ __align__(16) char SMEM[135168];
  char* LA = SMEM;
  char* LB = SMEM + 65536;

  const char* Ae = (const char*)A + (size_t)rowBase * K * 2;
  const char* Be = (const char*)B + ((size_t)e * Nn + colBase) * (size_t)K * 2;

  int tid = threadIdx.x;
  int lane = tid & 63, wave = tid >> 6;
  int wm = (wave >> 2) * 128, wn = (wave & 3) * 64;   // 2M x 4N waves, 128x64 each
  int frm = lane & 15, g = lane >> 4;

  // staging: thread covers row sr of each 64-row slab, 16B slot (tid&7);
  // source chunk = slot ^ (row&7)  (row&7 invariant across slabs)
  int sr = tid >> 3;
  int sch = (tid & 7) ^ (sr & 7);
  const char* aS = Ae + (size_t)sr * K * 2 + sch * 16;
  const char* bS = Be + (size_t)sr * K * 2 + sch * 16;
  size_t rstep = (size_t)64 * K * 2;   // 64-row slab stride in global

  // frag reads: row = wm|wn + fragidx*16 + frm; chunk(ks) = ks*4+g;
  // slot = chunk ^ (row&7) = chunk ^ (frm&7)
  int f7 = frm & 7;
  int sl0 = (g ^ f7) << 4;
  int sl1 = ((4 + g) ^ f7) << 4;
  const char* rA = LA + (wm + frm) * 128;
  const char* rB = LB + (wn + frm) * 128;

  f32x4 acc[8][4] = {};
  int kPer = (EPI == 1) ? (K >> 1) : K;
  int kLo = kz * kPer;
  int NT = kPer >> 6;                         // 16 (GEMM1) / 32 (GEMM2)
  const char* aP = aS + (size_t)kLo * 2;
  const char* bP = bS + (size_t)kLo * 2;

  auto stageA = [&](int t, int s, int b) {
    GLOAD_LDS16(aP + (size_t)t * 128 + (size_t)s * rstep,
                LA + b * 32768 + s * 8192 + tid * 16);
  };
  auto stageB = [&](int t, int s, int b) {
    GLOAD_LDS16(bP + (size_t)t * 128 + (size_t)s * rstep,
                LB + b * 32768 + s * 8192 + tid * 16);
  };

  // ---- prologue: tile 0 into buf 0, boundary-convention order
  stageB(0, 0, 0); stageB(0, 1, 0); stageB(0, 2, 0); stageB(0, 3, 0);
  stageA(0, 0, 0); stageA(0, 2, 0); stageA(0, 1, 0); stageA(0, 3, 0);
  asm volatile("s_waitcnt vmcnt(2)" ::: "memory");   // 6 oldest landed; A1,A3 in flight
  __builtin_amdgcn_sched_barrier(0);
  __builtin_amdgcn_s_barrier();

  for (int t = 0; t < NT; ++t) {
    int rb = t & 1, sb = rb ^ 1;
    const char* Ab = rA + rb * 32768;
    const char* Bb = rB + rb * 32768;
    bool pre = (t + 1 < NT);
    short8 bfr[4][2];
#pragma unroll 4
    for (int p = 0; p < 4; ++p) {
      short8 af[2][2];
      if (p == 0) {          // all B frags for this tile (own 64-col slab)
#pragma unroll
        for (int n = 0; n < 4; ++n) {
          bfr[n][0] = *(const short8*)(Bb + (n * 16) * 128 + sl0);
          bfr[n][1] = *(const short8*)(Bb + (n * 16) * 128 + sl1);
        }
      }
#pragma unroll
      for (int i = 0; i < 2; ++i) {   // A frags m = 2p, 2p+1
        af[i][0] = *(const short8*)(Ab + ((p * 2 + i) * 16) * 128 + sl0);
        af[i][1] = *(const short8*)(Ab + ((p * 2 + i) * 16) * 128 + sl1);
      }
      if (pre) {             // stage 2 slabs of tile t+1
        if (p == 0)      { stageB(t + 1, 0, sb); stageB(t + 1, 1, sb); }
        else if (p == 1) { stageB(t + 1, 2, sb); stageB(t + 1, 3, sb); }
        else if (p == 2) { stageA(t + 1, 0, sb); stageA(t + 1, 2, sb); }
        else             { stageA(t + 1, 1, sb); stageA(t + 1, 3, sb); }
      }
      __builtin_amdgcn_s_barrier();
      asm volatile("s_waitcnt lgkmcnt(0)" ::: "memory");
      __builtin_amdgcn_sched_barrier(0);
      __builtin_amdgcn_s_setprio(1);
#pragma unroll
      for (int ks = 0; ks < 2; ++ks)
#pragma unroll
        for (int i = 0; i < 2; ++i)
#pragma unroll
          for (int n = 0; n < 4; ++n)
            acc[p * 2 + i][n] = __builtin_amdgcn_mfma_f32_16x16x32_bf16(
                af[i][ks], bfr[n][ks], acc[p * 2 + i][n], 0, 0, 0);
      __builtin_amdgcn_s_setprio(0);
      if (p == 1) {          // A1,A3 of THIS tile must land before P2 reads
        if (pre) asm volatile("s_waitcnt vmcnt(4)" ::: "memory");
        else     asm volatile("s_waitcnt vmcnt(0)" ::: "memory");
        __builtin_amdgcn_sched_barrier(0);
      } else if (p == 3 && pre) {   // 6 oldest of tile t+1 before its P0
        asm volatile("s_waitcnt vmcnt(2)" ::: "memory");
        __builtin_amdgcn_sched_barrier(0);
      }
      __builtin_amdgcn_s_barrier();
    }
  }

  // C/D layout: col = lane&15, row = (lane>>4)*4 + reg   [m89/m91 verified]
  // Epilogue via LDS: scalar swizzled writes (2-way max), then full-row
  // coalesced 16B global stores (no partial-line write amplification).
  int cq = lane >> 4, cn = lane & 15;
  if (EPI == 0) {
    // bf16 256x256 = 128 KB; word-XOR swizzle spreads the 4 cq-rows
#pragma unroll
    for (int n = 0; n < 4; ++n) {
      int col = wn + n * 16 + cn;
      float bv = bias[e * Nn + colBase + col];
#pragma unroll
      for (int m = 0; m < 8; ++m) {
#pragma unroll
        for (int r = 0; r < 4; ++r) {
          int row = wm + m * 16 + cq * 4 + r;
          float v = acc[m][n][r] + bv;
          // tanh-approx GELU in sigmoid form: v*sigma(1.59577*(v+0.044715 v^3))
          float z = 1.5957691f * v * (1.0f + 0.044715f * v * v);
          v = v / (1.0f + __expf(-z));
          int w = (col >> 1) ^ (((row >> 2) & 3) << 3);
          *(__hip_bfloat16*)(SMEM + row * 512 + (w << 2) + ((col & 1) << 1)) =
              __float2bfloat16(v);
        }
      }
    }
    __syncthreads();
#pragma unroll
    for (int it = 0; it < 16; ++it) {
      int row = it * 16 + (tid >> 5), ck = tid & 31;
      int w = (ck << 2) ^ (((row >> 2) & 3) << 3);
      short8 v = *(const short8*)(SMEM + row * 512 + (w << 2));
      *(short8*)(Hout + (size_t)(rowBase + row) * Nn + colBase + ck * 8) = v;
    }
  } else {
    // fp32 256x256 = 256 KB: two 128-row halves through 133 KB LDS
    float* Pp = Pout + ((size_t)kz * ROWCAP + rowBase) * DDIM;
    int hhalf = wm >> 7;
#pragma unroll
    for (int h = 0; h < 2; ++h) {
      if (hhalf == h) {
#pragma unroll
        for (int n = 0; n < 4; ++n) {
          int col = wn + n * 16 + cn;
#pragma unroll
          for (int m = 0; m < 8; ++m) {
#pragma unroll
            for (int r = 0; r < 4; ++r) {
              int rl = m * 16 + cq * 4 + r;      // wm&127 == 0
              *(float*)(SMEM + rl * 1040 + col * 4) = acc[m][n][r];
            }
          }
        }
      }
      __syncthreads();
#pragma unroll
      for (int it = 0; it < 16; ++it) {
        int rr = it * 8 + (tid >> 6), ck = tid & 63;
        f32x4 v = *(const f32x4*)(SMEM + rr * 1040 + ck * 16);
        *(f32x4*)(Pp + (size_t)(h * 128 + rr) * DDIM + colBase + ck * 4) = v;
      }
      __syncthreads();
    }
  }
}

// ---------------------------------------------------------------- combine
// out[t][d] = sum_a g_a * (P0[row_a][d] + P1[row_a][d] + b2[e_a][d])
__global__ __launch_bounds__(256) void combine_kernel(
    const float* __restrict__ P, const float* __restrict__ b2,
    const int* __restrict__ counts, const int* __restrict__ eA,
    const int* __restrict__ sA, const float* __restrict__ gA,
    float* __restrict__ outF) {
  int t = blockIdx.x, c = threadIdx.x;   // c indexes float4 (256*4 = 1024 = D)
  int e0 = eA[2 * t], e1 = eA[2 * t + 1];
  int poff[NEXP + 1]; poff[0] = 0;
#pragma unroll
  for (int ee = 0; ee < NEXP; ++ee)
    poff[ee + 1] = poff[ee] + (((counts[ee] + 255) >> 8) << 8);
  int r0 = poff[e0] + sA[2 * t], r1 = poff[e1] + sA[2 * t + 1];
  float g0 = gA[2 * t], g1 = gA[2 * t + 1];
  float4 a0 = ((const float4*)(P + (size_t)r0 * DDIM))[c];
  float4 a1 = ((const float4*)(P + ((size_t)ROWCAP + r0) * DDIM))[c];
  float4 b0 = ((const float4*)(P + (size_t)r1 * DDIM))[c];
  float4 b1 = ((const float4*)(P + ((size_t)ROWCAP + r1) * DDIM))[c];
  float4 bb0 = ((const float4*)(b2 + (size_t)e0 * DDIM))[c];
  float4 bb1 = ((const float4*)(b2 + (size_t)e1 * DDIM))[c];
  float4 o;
  o.x = g0 * (a0.x + a1.x + bb0.x) + g1 * (b0.x + b1.x + bb1.x);
  o.y = g0 * (a0.y + a1.y + bb0.y) + g1 * (b0.y + b1.y + bb1.y);
  o.z = g0 * (a0.z + a1.z + bb0.z) + g1 * (b0.z + b1.z + bb1.z);
  o.w = g0 * (a0.w + a1.w + bb0.w) + g1 * (b0.w + b1.w + bb1.w);
  ((float4*)(outF + (size_t)t * DDIM))[c] = o;
}

// ---------------------------------------------------------------- launch
extern "C" void kernel_launch(void* const* d_in, const int* in_sizes, int n_in,
                              void* d_out, int out_size, void* d_ws, size_t ws_size,
                              hipStream_t stream) {
  const float* x  = (const float*)d_in[0];   // [4096][1024]
  const float* gw = (const float*)d_in[1];   // [1024][8]
  const float* gb = (const float*)d_in[2];   // [8]
  const float* w1 = (const float*)d_in[3];   // [8][1024][4096]
  const float* b1 = (const float*)d_in[4];   // [8][4096]
  const float* w2 = (const float*)d_in[5];   // [8][4096][1024]
  const float* b2 = (const float*)d_in[6];   // [8][1024]

  float* outF = (float*)d_out;                       // [4096][1024]
  float* outL = outF + (size_t)NTOK * DDIM;          // [4096][8]

  // workspace carve (~239 MB). P (split-K partials, fp32, 84 MB) aliases
  // wT1+Xg (88 MB), which are dead after GEMM1.
  size_t off = 0;
  char* base = (char*)d_ws;
  auto alloc = [&](size_t bytes) {
    void* r = base + off;
    off += (bytes + 255) & ~(size_t)255;
    return r;
  };
  __hip_bfloat16* wT1 = (__hip_bfloat16*)alloc((size_t)NEXP * HDIM * DDIM * 2);
  __hip_bfloat16* Xg  = (__hip_bfloat16*)alloc((size_t)ROWCAP * DDIM * 2);
  __hip_bfloat16* wT2 = (__hip_bfloat16*)alloc((size_t)NEXP * DDIM * HDIM * 2);
  __hip_bfloat16* Hact= (__hip_bfloat16*)alloc((size_t)ROWCAP * HDIM * 2);
  int*   tok    = (int*)alloc((size_t)NEXP * CAP * 4);
  float* gate   = (float*)alloc((size_t)NEXP * CAP * 4);
  int*   eA     = (int*)alloc((size_t)NTOK * 2 * 4);
  int*   sA     = (int*)alloc((size_t)NTOK * 2 * 4);
  float* gA     = (float*)alloc((size_t)NTOK * 2 * 4);
  int*   counts = (int*)alloc(64);
  float* P      = (float*)wT1;   // [2][ROWCAP][DDIM] fp32, aliases wT1+Xg

  hipMemsetAsync(counts, 0, 64, stream);
  gating_kernel<<<NTOK, 256, 0, stream>>>(x, gw, gb, outL, counts, tok, gate, eA, sA, gA);
  transpose_all<<<16384, 256, 0, stream>>>(w1, w2, wT1, wT2);
  gather_kernel<<<ROWCAP, 256, 0, stream>>>(x, counts, tok, gate, Xg);
  // GEMM1: 16 col-tiles (HDIM/256) x row-tiles
  moe_gemm<0><<<dim3(16, MAXTILES, 1), 512, 0, stream>>>(
      Xg, wT1, b1, Hact, nullptr, counts, DDIM, HDIM);
  // GEMM2: 4 col-tiles (DDIM/256) x 2 split-K, 1 combo per XCD
  moe_gemm<1><<<dim3(8, MAXTILES, 1), 512, 0, stream>>>(
      Hact, wT2, b2, nullptr, P, counts, HDIM, DDIM);
  combine_kernel<<<NTOK, 256, 0, stream>>>(P, b2, counts, eA, sA, gA, outF);
}

// Round 6
// 657.978 us; speedup vs baseline: 1.2668x; 1.0238x over previous
//
#include <hip/hip_runtime.h>
#include <hip/hip_bf16.h>
#include <math.h>

// Problem constants (B=2, T=2048, D=1024, H=4096, E=8, TOP_K=2)
#define NTOK 4096
#define DDIM 1024
#define HDIM 4096
#define NEXP 8
#define CAP  4096          // per-expert token-list capacity (worst case)
#define ROWCAP 10240       // max padded rows: 40 tiles * 256
#define MAXTILES 40        // sum ceil(c_e/256) <= 8192/256 + 8 = 40

typedef __attribute__((ext_vector_type(8))) short short8;   // 8 bf16 (4 VGPRs)
typedef __attribute__((ext_vector_type(4))) float f32x4;

#define GLOAD_LDS16(g, l) __builtin_amdgcn_global_load_lds( \
    (const __attribute__((address_space(1))) void*)(g),     \
    (__attribute__((address_space(3))) void*)(l), 16, 0, 0)

// schedule lookup from counts: ty -> (expert, rowBase). 256-row tiles.
__device__ __forceinline__ int tile_lookup(const int* __restrict__ counts,
                                           int ty, int& e, int& rowBase) {
  int acc = 0;
#pragma unroll
  for (int ee = 0; ee < NEXP; ++ee) {
    int tl = (counts[ee] + 255) >> 8;
    if (ty < tl) { e = ee; rowBase = acc + ty * 256; return 1; }
    ty -= tl; acc += tl << 8;
  }
  return 0;
}

// -------------------------------------------------- prep: transpose + gating
// Blocks [0,16384): weight transpose fp32 [E][R][C] -> bf16 [E][C][R].
//   Per thread: 4x4 fp32 block -> register transpose -> bf16 -> 4x b64
//   swizzled LDS writes (~2-way) -> b64 reads -> coalesced stores.
//   (replaces 16 scalar b32 writes with ~8-way conflicts)
// Blocks [16384,20480): gating for token t = blk-16384 (independent work,
//   merged to save a launch and fill the transpose tail).
__global__ __launch_bounds__(256) void prep_kernel(
    const float* __restrict__ x, const float* __restrict__ gw,
    const float* __restrict__ gb, float* __restrict__ logits_out,
    int* __restrict__ counts, int* __restrict__ tok, float* __restrict__ gate,
    int* __restrict__ eA, int* __restrict__ sA, float* __restrict__ gA,
    const float* __restrict__ w1, const float* __restrict__ w2,
    __hip_bfloat16* __restrict__ wT1, __hip_bfloat16* __restrict__ wT2) {
  __shared__ __align__(16) char PSM[8192];
  int tid = threadIdx.x;
  if (blockIdx.x < 16384) {
    // ------------------------------------------------ transpose 64x64 tile
    int id = blockIdx.x;
    const float* inp; __hip_bfloat16* outp; int R, C, bx, by;
    if (id < 8192) {                // w1: [e][1024][4096] -> wT1 [e][4096][1024]
      int e = id >> 10, rem = id & 1023;
      bx = rem & 63; by = rem >> 6;
      R = 1024; C = 4096;
      inp = w1 + (size_t)e * R * C; outp = wT1 + (size_t)e * R * C;
    } else {                        // w2: [e][4096][1024] -> wT2 [e][1024][4096]
      id -= 8192;
      int e = id >> 10, rem = id & 1023;
      bx = rem & 15; by = rem >> 4;
      R = 4096; C = 1024;
      inp = w2 + (size_t)e * R * C; outp = wT2 + (size_t)e * R * C;
    }
    int c0 = bx * 64, r0 = by * 64;
    int bx4 = tid & 15, by4 = tid >> 4;
    float4 v[4];
#pragma unroll
    for (int k = 0; k < 4; ++k)
      v[k] = *(const float4*)(inp + (size_t)(r0 + by4 * 4 + k) * C + c0 + bx4 * 4);
    unsigned short* T = (unsigned short*)PSM;   // bf16 [c][64 r], XOR-swizzled
#pragma unroll
    for (int j = 0; j < 4; ++j) {
      int c = bx4 * 4 + j;
      int xsw = ((c >> 3) & 7) << 3;            // XOR rows-bits 3..5 with c>>3
      union { unsigned short u[4]; uint2 q; } pk;
#pragma unroll
      for (int k = 0; k < 4; ++k) {
        __hip_bfloat16 h = __float2bfloat16((&v[k].x)[j]);
        pk.u[k] = *(unsigned short*)&h;
      }
      *(uint2*)(T + c * 64 + ((by4 * 4) ^ xsw)) = pk.q;
    }
    __syncthreads();
    int cc = tid >> 2, q = tid & 3;
    int xsw = ((cc >> 3) & 7) << 3;
    __hip_bfloat16* orow = outp + (size_t)(c0 + cc) * R + r0;
#pragma unroll
    for (int i = 0; i < 4; ++i) {
      int rb = i * 16 + q * 4;
      uint2 w = *(const uint2*)(T + cc * 64 + (rb ^ xsw));
      *(uint2*)(orow + rb) = w;
    }
  } else {
    // ------------------------------------------------ gating for one token
    int t = blockIdx.x - 16384;
    float p[NEXP];
#pragma unroll
    for (int e = 0; e < NEXP; ++e) p[e] = 0.f;
    const float* xr = x + (size_t)t * DDIM;
    for (int d = tid; d < DDIM; d += 256) {
      float xv = xr[d];
      const float* wr = gw + (size_t)d * NEXP;
#pragma unroll
      for (int e = 0; e < NEXP; ++e) p[e] += xv * wr[e];
    }
#pragma unroll
    for (int off = 32; off > 0; off >>= 1)
#pragma unroll
      for (int e = 0; e < NEXP; ++e) p[e] += __shfl_xor(p[e], off, 64);
    float (*red)[NEXP] = (float(*)[NEXP])PSM;
    int wave = tid >> 6, lane = tid & 63;
    if (lane == 0)
#pragma unroll
      for (int e = 0; e < NEXP; ++e) red[wave][e] = p[e];
    __syncthreads();
    if (tid < NEXP) {
      float v = red[0][tid] + red[1][tid] + red[2][tid] + red[3][tid] + gb[tid];
      logits_out[(size_t)t * NEXP + tid] = v;
      red[0][tid] = v;
    }
    __syncthreads();
    if (tid == 0) {
      float v[NEXP];
#pragma unroll
      for (int e = 0; e < NEXP; ++e) v[e] = red[0][e];
      int i0 = 0;
#pragma unroll
      for (int e = 1; e < NEXP; ++e) if (v[e] > v[i0]) i0 = e;
      int i1 = (i0 == 0) ? 1 : 0;
#pragma unroll
      for (int e = 0; e < NEXP; ++e) if (e != i0 && v[e] > v[i1]) i1 = e;
      float e1 = expf(v[i1] - v[i0]);          // v[i0] is the max
      float s = 1.f + e1;
      float g0 = 1.f / s, g1 = e1 / s;
      int s0 = atomicAdd(&counts[i0], 1);
      tok[i0 * CAP + s0] = t; gate[i0 * CAP + s0] = g0;
      int s1 = atomicAdd(&counts[i1], 1);
      tok[i1 * CAP + s1] = t; gate[i1 * CAP + s1] = g1;
      eA[2 * t] = i0; sA[2 * t] = s0; gA[2 * t] = g0;
      eA[2 * t + 1] = i1; sA[2 * t + 1] = s1; gA[2 * t + 1] = g1;
    }
  }
}

// ---------------------------------- gather tokens, scale by gate, cast bf16
__global__ __launch_bounds__(256) void gather_kernel(
    const float* __restrict__ x, const int* __restrict__ counts,
    const int* __restrict__ tok, const float* __restrict__ gate,
    __hip_bfloat16* __restrict__ Xg) {
  int r = blockIdx.x;
  int acc = 0, e = -1, idx = 0;
#pragma unroll
  for (int ee = 0; ee < NEXP; ++ee) {
    int sz = (((counts[ee] + 255) >> 8) << 8);
    if (e < 0 && r < acc + sz) { e = ee; idx = r - acc; }
    acc += sz;
  }
  if (e < 0) return;
  int tid = threadIdx.x;
  __hip_bfloat16* orow = Xg + (size_t)r * DDIM;
  if (idx < counts[e]) {
    int t = tok[e * CAP + idx];
    float g = gate[e * CAP + idx];
    float4 v = ((const float4*)(x + (size_t)t * DDIM))[tid];
    union { unsigned short u[4]; uint2 q; } pk;
    __hip_bfloat16 h0 = __float2bfloat16(v.x * g);
    __hip_bfloat16 h1 = __float2bfloat16(v.y * g);
    __hip_bfloat16 h2 = __float2bfloat16(v.z * g);
    __hip_bfloat16 h3 = __float2bfloat16(v.w * g);
    pk.u[0] = *(unsigned short*)&h0; pk.u[1] = *(unsigned short*)&h1;
    pk.u[2] = *(unsigned short*)&h2; pk.u[3] = *(unsigned short*)&h3;
    ((uint2*)orow)[tid] = pk.q;
  } else {
    uint2 z; z.x = 0; z.y = 0;
    ((uint2*)orow)[tid] = z;    // zero pad rows so GEMM1 reads zeros
  }
}

// ---------------------------------------------------------------- grouped GEMM
// m201-style 8-phase 256x256xBK64 schedule (T2+T3+T4+T5), 8 waves (512 thr),
// per-wave output 128x64 (2M x 4N wave grid), double-buffered 128 KB LDS.
// K-loop logic identical to round-4/5 (verified); NT loop unrolled x2 so the
// buffer parity (rb/sb) is compile-time -> LDS/stage addresses hoisted
// (targets GEMM1's 27.6% VALUBusy seen in PMC). LDS-staged coalesced
// epilogue (round-5, verified: WRITE_SIZE at floor).
template <int EPI>
__global__ __launch_bounds__(512, 2) void moe_gemm(
    const __hip_bfloat16* __restrict__ A, const __hip_bfloat16* __restrict__ B,
    const float* __restrict__ bias, __hip_bfloat16* __restrict__ Hout,
    float* __restrict__ Pout, const int* __restrict__ counts,
    int K, int Nn) {
  int f = blockIdx.y * gridDim.x + blockIdx.x;
  int xcd = f & 7, seq = f >> 3;
  int ct, ty, kz;
  if (EPI == 0) {            // 16 col tiles: 2 per XCD
    ct = xcd * 2 + (seq & 1); ty = seq >> 1; kz = 0;
  } else {                   // 4 col tiles x 2 kz = 8 combos: 1 per XCD
    ct = xcd & 3; kz = xcd >> 2; ty = seq;
  }
  int e, rowBase;
  if (!tile_lookup(counts, ty, e, rowBase)) return;
  int colBase = ct * 256;

  // union region: staging (2x32KB A + 2x32KB B) / epilogue stage (<=133120 B)
  __shared__ __align__(16) char SMEM[135168];
  char* LA = SMEM;
  char* LB = SMEM + 65536;

  const char* Ae = (const char*)A + (size_t)rowBase * K * 2;
  const char* Be = (const char*)B + ((size_t)e * Nn + colBase) * (size_t)K * 2;

  int tid = threadIdx.x;
  int lane = tid & 63, wave = tid >> 6;
  int wm = (wave >> 2) * 128, wn = (wave & 3) * 64;   // 2M x 4N waves, 128x64 each
  int frm = lane & 15, g = lane >> 4;

  // staging: thread covers row sr of each 64-row slab, 16B slot (tid&7);
  // source chunk = slot ^ (row&7)  (row&7 invariant across slabs)
  int sr = tid >> 3;
  int sch = (tid & 7) ^ (sr & 7);
  const char* aS = Ae + (size_t)sr * K * 2 + sch * 16;
  const char* bS = Be + (size_t)sr * K * 2 + sch * 16;
  size_t rstep = (size_t)64 * K * 2;   // 64-row slab stride in global

  // frag reads: row = wm|wn + fragidx*16 + frm; chunk(ks) = ks*4+g;
  // slot = chunk ^ (row&7) = chunk ^ (frm&7)
  int f7 = frm & 7;
  int sl0 = (g ^ f7) << 4;
  int sl1 = ((4 + g) ^ f7) << 4;
  const char* rA = LA + (wm + frm) * 128;
  const char* rB = LB + (wn + frm) * 128;

  f32x4 acc[8][4] = {};
  int kPer = (EPI == 1) ? (K >> 1) : K;
  int kLo = kz * kPer;
  int NT = kPer >> 6;                         // 16 (GEMM1) / 32 (GEMM2)
  const char* aP = aS + (size_t)kLo * 2;
  const char* bP = bS + (size_t)kLo * 2;

  auto stageA = [&](int t, int s, int b) {
    GLOAD_LDS16(aP + (size_t)t * 128 + (size_t)s * rstep,
                LA + b * 32768 + s * 8192 + tid * 16);
  };
  auto stageB = [&](int t, int s, int b) {
    GLOAD_LDS16(bP + (size_t)t * 128 + (size_t)s * rstep,
                LB + b * 32768 + s * 8192 + tid * 16);
  };

  // ---- prologue: tile 0 into buf 0, boundary-convention order
  stageB(0, 0, 0); stageB(0, 1, 0); stageB(0, 2, 0); stageB(0, 3, 0);
  stageA(0, 0, 0); stageA(0, 2, 0); stageA(0, 1, 0); stageA(0, 3, 0);
  asm volatile("s_waitcnt vmcnt(2)" ::: "memory");   // 6 oldest landed; A1,A3 in flight
  __builtin_amdgcn_sched_barrier(0);
  __builtin_amdgcn_s_barrier();

#pragma unroll 2
  for (int t = 0; t < NT; ++t) {
    int rb = t & 1, sb = rb ^ 1;
    const char* Ab = rA + rb * 32768;
    const char* Bb = rB + rb * 32768;
    bool pre = (t + 1 < NT);
    short8 bfr[4][2];
#pragma unroll 4
    for (int p = 0; p < 4; ++p) {
      short8 af[2][2];
      if (p == 0) {          // all B frags for this tile (own 64-col slab)
#pragma unroll
        for (int n = 0; n < 4; ++n) {
          bfr[n][0] = *(const short8*)(Bb + (n * 16) * 128 + sl0);
          bfr[n][1] = *(const short8*)(Bb + (n * 16) * 128 + sl1);
        }
      }
#pragma unroll
      for (int i = 0; i < 2; ++i) {   // A frags m = 2p, 2p+1
        af[i][0] = *(const short8*)(Ab + ((p * 2 + i) * 16) * 128 + sl0);
        af[i][1] = *(const short8*)(Ab + ((p * 2 + i) * 16) * 128 + sl1);
      }
      if (pre) {             // stage 2 slabs of tile t+1
        if (p == 0)      { stageB(t + 1, 0, sb); stageB(t + 1, 1, sb); }
        else if (p == 1) { stageB(t + 1, 2, sb); stageB(t + 1, 3, sb); }
        else if (p == 2) { stageA(t + 1, 0, sb); stageA(t + 1, 2, sb); }
        else             { stageA(t + 1, 1, sb); stageA(t + 1, 3, sb); }
      }
      __builtin_amdgcn_s_barrier();
      asm volatile("s_waitcnt lgkmcnt(0)" ::: "memory");
      __builtin_amdgcn_sched_barrier(0);
      __builtin_amdgcn_s_setprio(1);
#pragma unroll
      for (int ks = 0; ks < 2; ++ks)
#pragma unroll
        for (int i = 0; i < 2; ++i)
#pragma unroll
          for (int n = 0; n < 4; ++n)
            acc[p * 2 + i][n] = __builtin_amdgcn_mfma_f32_16x16x32_bf16(
                af[i][ks], bfr[n][ks], acc[p * 2 + i][n], 0, 0, 0);
      __builtin_amdgcn_s_setprio(0);
      if (p == 1) {          // A1,A3 of THIS tile must land before P2 reads
        if (pre) asm volatile("s_waitcnt vmcnt(4)" ::: "memory");
        else     asm volatile("s_waitcnt vmcnt(0)" ::: "memory");
        __builtin_amdgcn_sched_barrier(0);
      } else if (p == 3 && pre) {   // 6 oldest of tile t+1 before its P0
        asm volatile("s_waitcnt vmcnt(2)" ::: "memory");
        __builtin_amdgcn_sched_barrier(0);
      }
      __builtin_amdgcn_s_barrier();
    }
  }

  // C/D layout: col = lane&15, row = (lane>>4)*4 + reg   [m89/m91 verified]
  // Epilogue via LDS: scalar swizzled writes (2-way max), then full-row
  // coalesced 16B global stores (no partial-line write amplification).
  int cq = lane >> 4, cn = lane & 15;
  if (EPI == 0) {
    // bf16 256x256 = 128 KB; word-XOR swizzle spreads the 4 cq-rows
#pragma unroll
    for (int n = 0; n < 4; ++n) {
      int col = wn + n * 16 + cn;
      float bv = bias[e * Nn + colBase + col];
#pragma unroll
      for (int m = 0; m < 8; ++m) {
#pragma unroll
        for (int r = 0; r < 4; ++r) {
          int row = wm + m * 16 + cq * 4 + r;
          float v = acc[m][n][r] + bv;
          // tanh-approx GELU in sigmoid form: v*sigma(1.59577*(v+0.044715 v^3))
          float z = 1.5957691f * v * (1.0f + 0.044715f * v * v);
          v = v / (1.0f + __expf(-z));
          int w = (col >> 1) ^ (((row >> 2) & 3) << 3);
          *(__hip_bfloat16*)(SMEM + row * 512 + (w << 2) + ((col & 1) << 1)) =
              __float2bfloat16(v);
        }
      }
    }
    __syncthreads();
#pragma unroll
    for (int it = 0; it < 16; ++it) {
      int row = it * 16 + (tid >> 5), ck = tid & 31;
      int w = (ck << 2) ^ (((row >> 2) & 3) << 3);
      short8 v = *(const short8*)(SMEM + row * 512 + (w << 2));
      *(short8*)(Hout + (size_t)(rowBase + row) * Nn + colBase + ck * 8) = v;
    }
  } else {
    // fp32 256x256 = 256 KB: two 128-row halves through 133 KB LDS
    float* Pp = Pout + ((size_t)kz * ROWCAP + rowBase) * DDIM;
    int hhalf = wm >> 7;
#pragma unroll
    for (int h = 0; h < 2; ++h) {
      if (hhalf == h) {
#pragma unroll
        for (int n = 0; n < 4; ++n) {
          int col = wn + n * 16 + cn;
#pragma unroll
          for (int m = 0; m < 8; ++m) {
#pragma unroll
            for (int r = 0; r < 4; ++r) {
              int rl = m * 16 + cq * 4 + r;      // wm&127 == 0
              *(float*)(SMEM + rl * 1040 + col * 4) = acc[m][n][r];
            }
          }
        }
      }
      __syncthreads();
#pragma unroll
      for (int it = 0; it < 16; ++it) {
        int rr = it * 8 + (tid >> 6), ck = tid & 63;
        f32x4 v = *(const f32x4*)(SMEM + rr * 1040 + ck * 16);
        *(f32x4*)(Pp + (size_t)(h * 128 + rr) * DDIM + colBase + ck * 4) = v;
      }
      __syncthreads();
    }
  }
}

// ---------------------------------------------------------------- combine
// out[t][d] = sum_a g_a * (P0[row_a][d] + P1[row_a][d] + b2[e_a][d])
__global__ __launch_bounds__(256) void combine_kernel(
    const float* __restrict__ P, const float* __restrict__ b2,
    const int* __restrict__ counts, const int* __restrict__ eA,
    const int* __restrict__ sA, const float* __restrict__ gA,
    float* __restrict__ outF) {
  int t = blockIdx.x, c = threadIdx.x;   // c indexes float4 (256*4 = 1024 = D)
  int e0 = eA[2 * t], e1 = eA[2 * t + 1];
  int poff[NEXP + 1]; poff[0] = 0;
#pragma unroll
  for (int ee = 0; ee < NEXP; ++ee)
    poff[ee + 1] = poff[ee] + (((counts[ee] + 255) >> 8) << 8);
  int r0 = poff[e0] + sA[2 * t], r1 = poff[e1] + sA[2 * t + 1];
  float g0 = gA[2 * t], g1 = gA[2 * t + 1];
  float4 a0 = ((const float4*)(P + (size_t)r0 * DDIM))[c];
  float4 a1 = ((const float4*)(P + ((size_t)ROWCAP + r0) * DDIM))[c];
  float4 b0 = ((const float4*)(P + (size_t)r1 * DDIM))[c];
  float4 b1 = ((const float4*)(P + ((size_t)ROWCAP + r1) * DDIM))[c];
  float4 bb0 = ((const float4*)(b2 + (size_t)e0 * DDIM))[c];
  float4 bb1 = ((const float4*)(b2 + (size_t)e1 * DDIM))[c];
  float4 o;
  o.x = g0 * (a0.x + a1.x + bb0.x) + g1 * (b0.x + b1.x + bb1.x);
  o.y = g0 * (a0.y + a1.y + bb0.y) + g1 * (b0.y + b1.y + bb1.y);
  o.z = g0 * (a0.z + a1.z + bb0.z) + g1 * (b0.z + b1.z + bb1.z);
  o.w = g0 * (a0.w + a1.w + bb0.w) + g1 * (b0.w + b1.w + bb1.w);
  ((float4*)(outF + (size_t)t * DDIM))[c] = o;
}

// ---------------------------------------------------------------- launch
extern "C" void kernel_launch(void* const* d_in, const int* in_sizes, int n_in,
                              void* d_out, int out_size, void* d_ws, size_t ws_size,
                              hipStream_t stream) {
  const float* x  = (const float*)d_in[0];   // [4096][1024]
  const float* gw = (const float*)d_in[1];   // [1024][8]
  const float* gb = (const float*)d_in[2];   // [8]
  const float* w1 = (const float*)d_in[3];   // [8][1024][4096]
  const float* b1 = (const float*)d_in[4];   // [8][4096]
  const float* w2 = (const float*)d_in[5];   // [8][4096][1024]
  const float* b2 = (const float*)d_in[6];   // [8][1024]

  float* outF = (float*)d_out;                       // [4096][1024]
  float* outL = outF + (size_t)NTOK * DDIM;          // [4096][8]

  // workspace carve (~239 MB). P (split-K partials, fp32, 84 MB) aliases
  // wT1+Xg (88 MB), which are dead after GEMM1.
  size_t off = 0;
  char* base = (char*)d_ws;
  auto alloc = [&](size_t bytes) {
    void* r = base + off;
    off += (bytes + 255) & ~(size_t)255;
    return r;
  };
  __hip_bfloat16* wT1 = (__hip_bfloat16*)alloc((size_t)NEXP * HDIM * DDIM * 2);
  __hip_bfloat16* Xg  = (__hip_bfloat16*)alloc((size_t)ROWCAP * DDIM * 2);
  __hip_bfloat16* wT2 = (__hip_bfloat16*)alloc((size_t)NEXP * DDIM * HDIM * 2);
  __hip_bfloat16* Hact= (__hip_bfloat16*)alloc((size_t)ROWCAP * HDIM * 2);
  int*   tok    = (int*)alloc((size_t)NEXP * CAP * 4);
  float* gate   = (float*)alloc((size_t)NEXP * CAP * 4);
  int*   eA     = (int*)alloc((size_t)NTOK * 2 * 4);
  int*   sA     = (int*)alloc((size_t)NTOK * 2 * 4);
  float* gA     = (float*)alloc((size_t)NTOK * 2 * 4);
  int*   counts = (int*)alloc(64);
  float* P      = (float*)wT1;   // [2][ROWCAP][DDIM] fp32, aliases wT1+Xg

  hipMemsetAsync(counts, 0, 64, stream);
  prep_kernel<<<16384 + NTOK, 256, 0, stream>>>(
      x, gw, gb, outL, counts, tok, gate, eA, sA, gA, w1, w2, wT1, wT2);
  gather_kernel<<<ROWCAP, 256, 0, stream>>>(x, counts, tok, gate, Xg);
  // GEMM1: 16 col-tiles (HDIM/256) x row-tiles
  moe_gemm<0><<<dim3(16, MAXTILES, 1), 512, 0, stream>>>(
      Xg, wT1, b1, Hact, nullptr, counts, DDIM, HDIM);
  // GEMM2: 4 col-tiles (DDIM/256) x 2 split-K, 1 combo per XCD
  moe_gemm<1><<<dim3(8, MAXTILES, 1), 512, 0, stream>>>(
      Hact, wT2, b2, nullptr, P, counts, HDIM, DDIM);
  combine_kernel<<<NTOK, 256, 0, stream>>>(P, b2, counts, eA, sA, gA, outF);
}